// Round 8
// baseline (726.575 us; speedup 1.0000x reference)
//
#include <hip/hip_runtime.h>
#include <cmath>
#include <cstdint>

#define Bc   16
#define Cc   128
#define Nc   2000
#define Lc   128      // sequence length for mamba = C
#define DIc  4000
#define Sc   8
#define RKc  125      // DT_RANK
#define E2c  8000     // 2*DI
#define EXc  141      // DT_RANK + 2*S

// padded dims for MFMA gemm #1 (xz = outn @ W_in^T)
#define KP1  2016     // 2000 -> mult of 32
#define NP1  8064     // 8000 -> mult of 128

__device__ __forceinline__ unsigned short f2bf(float f) {
  union { float f; unsigned int u; } v; v.f = f;
  unsigned int r = v.u + 0x7FFFu + ((v.u >> 16) & 1u);
  return (unsigned short)(r >> 16);
}
__device__ __forceinline__ float bf2f(unsigned short u) {
  union { unsigned int i; float f; } v; v.i = ((unsigned int)u) << 16; return v.f;
}

// ------------------------------------------------------------------
// K1: per-(b,c) instance-norm stats over N (mean, biased var)
// ------------------------------------------------------------------
__global__ void inorm_stats(const float* __restrict__ in,
                            float* __restrict__ mout,
                            float* __restrict__ vout) {
  int bc = blockIdx.x;
  const float* p = in + (long)bc * Nc;
  float s = 0.f, sq = 0.f;
  for (int i = threadIdx.x; i < Nc; i += blockDim.x) {
    float x = p[i]; s += x; sq += x * x;
  }
  #pragma unroll
  for (int o = 32; o > 0; o >>= 1) {
    s  += __shfl_down(s, o, 64);
    sq += __shfl_down(sq, o, 64);
  }
  __shared__ float ss[4], sqq[4];
  int w = threadIdx.x >> 6, lane = threadIdx.x & 63;
  if (lane == 0) { ss[w] = s; sqq[w] = sq; }
  __syncthreads();
  if (threadIdx.x == 0) {
    s  = ss[0] + ss[1] + ss[2] + ss[3];
    sq = sqq[0] + sqq[1] + sqq[2] + sqq[3];
    float mean = s / Nc;
    float var  = sq / Nc - mean * mean;
    mout[bc] = mean; vout[bc] = var;
  }
}

// ------------------------------------------------------------------
// K2: bn scale; inorm output has zero mean per (b,c) so bn mean==0,
// bn var = avg_b[ v/(v+1e-3) ]
// ------------------------------------------------------------------
__global__ void bn_scale(const float* __restrict__ v, float* __restrict__ bnsc) {
  int c = threadIdx.x;
  if (c >= Cc) return;
  float s = 0.f;
  for (int b = 0; b < Bc; b++) {
    float vv = v[b * Cc + c];
    s += vv / (vv + 1e-3f);
  }
  bnsc[c] = rsqrtf(s / Bc + 1e-5f);
}

// ------------------------------------------------------------------
// K3: h^T = relu( inorm(x) * bnscale[c] * g[c] + b[c] ) transposed to
// (b, n, c) bf16 via LDS tile — the MFMA B^T operand layout.
// ------------------------------------------------------------------
__global__ void compute_h_t(const float* __restrict__ in,
                            const float* __restrict__ m,
                            const float* __restrict__ v,
                            const float* __restrict__ bnsc,
                            const float* __restrict__ g,
                            const float* __restrict__ bb,
                            unsigned short* __restrict__ hT) {
  int b  = blockIdx.y;
  int n0 = blockIdx.x * 64;
  __shared__ unsigned short tile[64][132];
  int t  = threadIdx.x;
  int nl = t & 63, cb = t >> 6;
  int n  = n0 + nl;
  #pragma unroll 4
  for (int p = 0; p < 32; p++) {
    int c = p * 4 + cb;
    float val = 0.f;
    if (n < Nc) {
      int bc = b * Cc + c;
      float xn = (in[(long)bc * Nc + n] - m[bc]) * rsqrtf(v[bc] + 1e-3f);
      val = fmaxf(xn * bnsc[c] * g[c] + bb[c], 0.f);
    }
    tile[nl][c] = f2bf(val);
  }
  __syncthreads();
  int r = t >> 2, c0 = (t & 3) * 32;
  int nr = n0 + r;
  if (nr < Nc) {
    unsigned int* dst = (unsigned int*)(hT + ((long)b * 2048 + nr) * 128 + c0);
    const unsigned short* src = &tile[r][c0];
    #pragma unroll
    for (int j = 0; j < 16; j++)
      dst[j] = *(const unsigned int*)(src + 2 * j);
  }
}

// ------------------------------------------------------------------
// reduce ns slices (each `stride` apart) into dst; accum!=0 -> dst += sum
// ------------------------------------------------------------------
__global__ void reduce_slices(const float* __restrict__ sl, float* __restrict__ dst,
                              long stride, int ns, int total, int accum) {
  int i = blockIdx.x * 256 + threadIdx.x;
  if (i >= total) return;
  float s = accum ? dst[i] : 0.f;
  for (int k = 0; k < ns; k++) s += sl[(long)k * stride + i];
  dst[i] = s;
}

// ------------------------------------------------------------------
// reduce 4 xdbl slices (2048 x 256 each) -> xdbl f32 (2048 x 141)
// and xdbl_b bf16 (2048 x 128: cols 0..124, 125..127 zero)
// ------------------------------------------------------------------
__global__ void reduce_xdbl(const float* __restrict__ sl,
                            float* __restrict__ xd,
                            unsigned short* __restrict__ xdb) {
  int i = blockIdx.x * 256 + threadIdx.x;
  if (i >= 2048 * 144) return;
  int row = i / 144, c = i - row * 144;
  float s = 0.f;
  if (c < EXc) {
    #pragma unroll
    for (int k = 0; k < 4; k++) s += sl[(long)k * (2048 * 256) + (long)row * 256 + c];
    xd[(long)row * EXc + c] = s;
  }
  if (c < 128) xdb[(long)row * 128 + c] = f2bf(c < RKc ? s : 0.f);
}

// ------------------------------------------------------------------
// convert f32 (Rsrc x Csrc) to bf16 (R x Cdst) with zero padding
// ------------------------------------------------------------------
__global__ void cvt_pad_bf16(const float* __restrict__ src, unsigned short* __restrict__ dst,
                             int R, int Cdst, int Rsrc, int Csrc) {
  long i = (long)blockIdx.x * 256 + threadIdx.x;
  long total = (long)R * Cdst;
  if (i >= total) return;
  int r = (int)(i / Cdst), c = (int)(i - (long)r * Cdst);
  float v = (r < Rsrc && c < Csrc) ? src[(long)r * Csrc + c] : 0.f;
  dst[i] = f2bf(v);
}

// ------------------------------------------------------------------
// K4: LayerNorm rows -> writes bf16, K-padded to KP1 with zeros
// ------------------------------------------------------------------
__global__ void ln_rows(const float* __restrict__ in,
                        const float* __restrict__ lw,
                        const float* __restrict__ lb,
                        unsigned short* __restrict__ An) {
  int row = blockIdx.x;
  const float* p = in + (long)row * Nc;
  float s = 0.f, sq = 0.f;
  for (int i = threadIdx.x; i < Nc; i += blockDim.x) {
    float x = p[i]; s += x; sq += x * x;
  }
  #pragma unroll
  for (int o = 32; o > 0; o >>= 1) {
    s  += __shfl_down(s, o, 64);
    sq += __shfl_down(sq, o, 64);
  }
  __shared__ float ss[4], sqq[4];
  __shared__ float smean, srstd;
  int w = threadIdx.x >> 6, lane = threadIdx.x & 63;
  if (lane == 0) { ss[w] = s; sqq[w] = sq; }
  __syncthreads();
  if (threadIdx.x == 0) {
    s  = ss[0] + ss[1] + ss[2] + ss[3];
    sq = sqq[0] + sqq[1] + sqq[2] + sqq[3];
    float mean = s / Nc;
    float var  = sq / Nc - mean * mean;
    smean = mean; srstd = rsqrtf(var + 1e-5f);
  }
  __syncthreads();
  float mu = smean, rs = srstd;
  for (int i = threadIdx.x; i < KP1; i += blockDim.x) {
    float v = 0.f;
    if (i < Nc) v = (p[i] - mu) * rs * lw[i] + lb[i];
    An[(long)row * KP1 + i] = f2bf(v);
  }
}

// ------------------------------------------------------------------
// bf16 MFMA GEMM, B^T layout: C[i][j] = sum_k A[i][k] * B[j][k]
// 128x128 tile, 4 waves (2x2), each 4x4 of mfma_f32_16x16x32_bf16.
// mode 0: grid (jTiles, iTiles, batch*KS+ks) linear decode.
// mode 1: 1D grid 1024, XCD swizzle for 16i x 64j (W_in): all i-blocks
//         of a j-tile share L%8 -> same XCD L2 caches that B tile once.
//         Blocks with j0 >= jret return (B padding rows not allocated).
// mode 2: 1D grid 512, XCD swizzle for 16i x 16j x KS2 (W_out).
// epi: 0 none; 1 softplus(v+ebias[gj]); 2 silu(v) for j>=DIc; 3 v+ebias[gi](+addp)
// obf: write bf16 instead of f32.
// ------------------------------------------------------------------
typedef short v8s __attribute__((ext_vector_type(8)));
typedef float v4f __attribute__((ext_vector_type(4)));

typedef const __attribute__((address_space(1))) unsigned int* as1_cu32p;
typedef __attribute__((address_space(3))) unsigned int* as3_u32p;

__device__ __forceinline__ void gload_lds16(const unsigned short* g, unsigned short* l) {
  __builtin_amdgcn_global_load_lds((as1_cu32p)(uintptr_t)g,
                                   (as3_u32p)(uintptr_t)l, 16, 0, 0);
}

__global__ __launch_bounds__(256, 4)
void gemm_mfma_bt(const unsigned short* __restrict__ A,
                  const unsigned short* __restrict__ B,
                  float* C, int NN, int K, int lda, int ldb, int ldc,
                  long sA, long sB, long sC,
                  int KS, int Klen, long sliceStride,
                  int epi, const float* __restrict__ ebias,
                  const float* __restrict__ addp,
                  int mode, int jret, int obf) {
  __shared__ unsigned short As[128 * 32];
  __shared__ unsigned short Bs[128 * 32];

  int i0, j0, ks = 0, batch = 0;
  if (mode == 1) {
    int L = blockIdx.x;
    int q = L & 7, w = L >> 3;
    i0 = (w & 15) * 128;
    int jg = w >> 4;
    j0 = (jg * 8 + q) * 128;
    if (j0 >= jret) return;
  } else if (mode == 2) {
    int L = blockIdx.x;
    int q = L & 7, w = L >> 3;
    i0 = (w & 15) * 128;
    int r = w >> 4;            // 0..3
    ks = r >> 1;
    j0 = (q * 2 + (r & 1)) * 128;
  } else {
    int z = blockIdx.z;
    batch = z / KS; ks = z - batch * KS;
    i0 = blockIdx.y * 128; j0 = blockIdx.x * 128;
  }

  const unsigned short* Ab = A + (long)batch * sA;
  const unsigned short* Bb = B + (long)batch * sB;
  float* Cs = C + (long)batch * sC + (long)ks * sliceStride;
  const float* X = addp ? addp + (long)batch * sC : nullptr;

  int k0 = ks * Klen;
  int kend = min(K, k0 + Klen);

  int t = threadIdx.x;
  int wave = t >> 6, lane = t & 63;
  int wm = wave >> 1, wn = wave & 1;

  int srow = lane >> 2;     // 0..15
  int scol = lane & 3;      // k-chunk (8 bf16 = 16B)
  const unsigned short* gA0 = Ab + (long)(i0 + wave * 32 + srow) * lda + scol * 8;
  const unsigned short* gA1 = gA0 + (long)16 * lda;
  const unsigned short* gB0 = Bb + (long)(j0 + wave * 32 + srow) * ldb + scol * 8;
  const unsigned short* gB1 = gB0 + (long)16 * ldb;
  unsigned short* lA0 = As + (wave * 32) * 32;
  unsigned short* lA1 = As + (wave * 32 + 16) * 32;
  unsigned short* lB0 = Bs + (wave * 32) * 32;
  unsigned short* lB1 = Bs + (wave * 32 + 16) * 32;

  int fr = lane & 15;       // input-frag row index
  int kq = lane >> 4;       // k-quad (8 elements each)

  v4f acc[4][4] = {};

  for (int kt = k0; kt < kend; kt += 32) {
    gload_lds16(gA0 + kt, lA0);
    gload_lds16(gA1 + kt, lA1);
    gload_lds16(gB0 + kt, lB0);
    gload_lds16(gB1 + kt, lB1);
    __syncthreads();

    v8s af[4], bfr[4];
    #pragma unroll
    for (int mt = 0; mt < 4; mt++)
      af[mt] = *(const v8s*)&As[(wm * 64 + mt * 16 + fr) * 32 + kq * 8];
    #pragma unroll
    for (int nt = 0; nt < 4; nt++)
      bfr[nt] = *(const v8s*)&Bs[(wn * 64 + nt * 16 + fr) * 32 + kq * 8];

    #pragma unroll
    for (int mt = 0; mt < 4; mt++)
      #pragma unroll
      for (int nt = 0; nt < 4; nt++)
        acc[mt][nt] = __builtin_amdgcn_mfma_f32_16x16x32_bf16(
            af[mt], bfr[nt], acc[mt][nt], 0, 0, 0);
    __syncthreads();
  }

  // C/D layout: row=(lane>>4)*4+reg (A's m), col=lane&15 (B's n)
  int orow = (lane >> 4) * 4;
  int ocol = lane & 15;
  #pragma unroll
  for (int mt = 0; mt < 4; mt++) {
    #pragma unroll
    for (int nt = 0; nt < 4; nt++) {
      int gi = i0 + wm * 64 + mt * 16 + orow;
      int gj = j0 + wn * 64 + nt * 16 + ocol;
      if (gj >= NN) continue;
      #pragma unroll
      for (int r = 0; r < 4; r++) {
        long idx = (long)(gi + r) * ldc + gj;
        float v = acc[mt][nt][r];
        if (epi == 1) {
          float tr = v + ebias[gj];
          v = fmaxf(tr, 0.f) + log1pf(__expf(-fabsf(tr)));  // softplus
        } else if (epi == 2) {
          if (gj >= DIc) v = v / (1.f + __expf(-v));        // silu on z half
        } else if (epi == 3) {
          v += ebias[gi + r];
          if (X) v += X[idx];
        }
        if (obf) ((unsigned short*)Cs)[idx] = f2bf(v);
        else Cs[idx] = v;
      }
    }
  }
}

// ------------------------------------------------------------------
// K6: depthwise causal conv (DCONV=4) + silu; xz is bf16 now.
// writes f32 xc (scan input) and bf16 xcb (GEMM A operand)
// ------------------------------------------------------------------
__global__ void dwconv_silu(const unsigned short* __restrict__ xzb,
                            const float4* __restrict__ cw,
                            const float* __restrict__ cb,
                            float* __restrict__ xc,
                            unsigned short* __restrict__ xcb, int total) {
  int i = blockIdx.x * 256 + threadIdx.x;
  if (i >= total) return;
  int d  = i % DIc;
  int bl = i / DIc;
  int l  = bl % Lc;
  int b  = bl / Lc;
  float4 w = cw[d];
  float acc = cb[d];
  long rowbase = (long)(b * Lc) * E2c + d;
  int l0 = l - 3;
  if (l0     >= 0) acc += bf2f(xzb[rowbase + (long)l0       * E2c]) * w.x;
  if (l0 + 1 >= 0) acc += bf2f(xzb[rowbase + (long)(l0 + 1) * E2c]) * w.y;
  if (l0 + 2 >= 0) acc += bf2f(xzb[rowbase + (long)(l0 + 2) * E2c]) * w.z;
  acc += bf2f(xzb[rowbase + (long)l * E2c]) * w.w;
  float sv = acc / (1.f + __expf(-acc));
  xc[i] = sv;
  xcb[i] = f2bf(sv);
}

// ------------------------------------------------------------------
// K9: selective scan, 1 thread per (b,d), software-pipelined.
// dtv pre-softplus'd (dt-GEMM epilogue); z pre-silu'd bf16 (W_in epi).
// ------------------------------------------------------------------
#define SCU 4
__global__ __launch_bounds__(256)
void scan_kernel(const float* __restrict__ dtv,
                 const float* __restrict__ xdbl,
                 const float* __restrict__ xc,
                 const unsigned short* __restrict__ xzb,
                 const float* __restrict__ A_log,
                 const float* __restrict__ D_p,
                 unsigned short* __restrict__ yb) {
  int d = blockIdx.x * 256 + threadIdx.x;
  int b = blockIdx.y;
  if (d >= DIc) return;
  float Av[Sc];
  #pragma unroll
  for (int s = 0; s < Sc; s++) Av[s] = -__expf(A_log[d * Sc + s]);
  float Dp = D_p[d];
  float h[Sc];
  #pragma unroll
  for (int s = 0; s < Sc; s++) h[s] = 0.f;

  long base  = (long)(b * Lc) * DIc + d;
  long zbase = (long)(b * Lc) * E2c + DIc + d;
  const float* xrow = xdbl + (long)(b * Lc) * EXc + RKc;

  float d0[SCU], u0[SCU], z0[SCU], B0[SCU][Sc], C0[SCU][Sc];
  float d1[SCU], u1[SCU], z1[SCU], B1[SCU][Sc], C1[SCU][Sc];

#define LOADG(g, dd, uu, zz, BB, CC)                                        \
  { int l0_ = (g) * SCU;                                                    \
    _Pragma("unroll")                                                       \
    for (int u = 0; u < SCU; u++) {                                         \
      long idx = base + (long)(l0_ + u) * DIc;                              \
      dd[u] = dtv[idx];                                                     \
      uu[u] = xc[idx];                                                      \
      zz[u] = bf2f(xzb[zbase + (long)(l0_ + u) * E2c]);                     \
      const float* xr = xrow + (long)(l0_ + u) * EXc;                       \
      _Pragma("unroll")                                                     \
      for (int s = 0; s < Sc; s++) { BB[u][s] = xr[s]; CC[u][s] = xr[Sc + s]; } \
    } }

#define COMPG(g, dd, uu, zz, BB, CC)                                        \
  { int l0_ = (g) * SCU;                                                    \
    _Pragma("unroll")                                                       \
    for (int u = 0; u < SCU; u++) {                                         \
      float dv = dd[u], uv = uu[u];                                         \
      float du = dv * uv;                                                   \
      float p = 0.f;                                                        \
      _Pragma("unroll")                                                     \
      for (int s = 0; s < Sc; s++) {                                        \
        float dA = __expf(dv * Av[s]);                                      \
        h[s] = dA * h[s] + du * BB[u][s];                                   \
        p += h[s] * CC[u][s];                                               \
      }                                                                     \
      yb[base + (long)(l0_ + u) * DIc] = f2bf((p + uv * Dp) * zz[u]);       \
    } }

  LOADG(0, d0, u0, z0, B0, C0);
  #pragma unroll 1
  for (int g = 0; g < Lc / SCU; g += 2) {
    LOADG(g + 1, d1, u1, z1, B1, C1);
    COMPG(g, d0, u0, z0, B0, C0);
    if (g + 2 < Lc / SCU) LOADG(g + 2, d0, u0, z0, B0, C0);
    COMPG(g + 1, d1, u1, z1, B1, C1);
  }
#undef LOADG
#undef COMPG
}

// ------------------------------------------------------------------
// launch
// ------------------------------------------------------------------
extern "C" void kernel_launch(void* const* d_in, const int* in_sizes, int n_in,
                              void* d_out, int out_size, void* d_ws, size_t ws_size,
                              hipStream_t stream) {
  const float* x       = (const float*)d_in[0];
  const float* bn1_g   = (const float*)d_in[1];
  const float* bn1_b   = (const float*)d_in[2];
  const float* conv1_w = (const float*)d_in[3];
  const float* conv1_b = (const float*)d_in[4];
  const float* ln_w    = (const float*)d_in[5];
  const float* ln_b    = (const float*)d_in[6];
  const float* W_in    = (const float*)d_in[7];
  const float* convm_w = (const float*)d_in[8];
  const float* convm_b = (const float*)d_in[9];
  const float* W_x     = (const float*)d_in[10];
  const float* W_dt    = (const float*)d_in[11];
  const float* b_dt    = (const float*)d_in[12];
  const float* A_log   = (const float*)d_in[13];
  const float* D_p     = (const float*)d_in[14];
  const float* W_out   = (const float*)d_in[15];
  const float* bn3_g   = (const float*)d_in[16];
  const float* bn3_b   = (const float*)d_in[17];
  const float* conv3_w = (const float*)d_in[18];
  const float* conv3_b = (const float*)d_in[19];
  float* out = (float*)d_out;
  float* ws  = (float*)d_ws;

  const int TOT  = Bc * Cc * Nc;     // 4,096,000
  const int ROWS = Bc * Lc;          // 2048

  // ws layout (floats):
  float* m1    = ws;                         // 2048
  float* v1    = ws + 2048;                  // 2048
  float* bnsc  = ws + 4096;                  // 128
  float* h     = ws + 8192;                  // 4,096,000 f32 region
  float* out1  = h    + (long)TOT;           // 4,096,000 f32
  float* outn  = out1 + (long)TOT;           // 4,096,000 f32 region
  float* xz    = outn + (long)TOT;           // 16,384,000 f32 region
  float* xc    = xz   + (long)ROWS * E2c;    // 8,192,000 f32
  float* xdbl  = xc   + (long)ROWS * DIc;    // 288,768 f32
  float* dtb   = xdbl + (long)ROWS * EXc;    // 8,192,000 f32 (holds dtv after dt gemm)

  // region reuse (stream-order lifetimes verified):
  unsigned short* An      = (unsigned short*)outn;             // live: ln_rows -> W_in gemm
  unsigned short* Bwin    = (unsigned short*)dtb;              // live: cvt -> W_in gemm
  unsigned short* Bwx     = (unsigned short*)outn;             // after An dead
  unsigned short* Bwdt    = (unsigned short*)(outn + 512000);
  float*          xdbl_sl = outn + 800000;
  unsigned short* xdbl_b  = (unsigned short*)(outn + 2900000);
  unsigned short* W1b     = (unsigned short*)(outn + 3100000);
  unsigned short* W3b     = (unsigned short*)(outn + 3200000); // live to end
  unsigned short* hT      = (unsigned short*)h;
  unsigned short* xcb     = (unsigned short*)h;                // live: dwconv -> xdbl gemm
  unsigned short* Bwout   = (unsigned short*)h;                // live: cvt -> W_out gemm
  unsigned short* xzb     = (unsigned short*)xz;               // bf16 xz (2048x8000); live: W_in gemm -> scan
  unsigned short* yb      = (unsigned short*)out;              // live: scan -> W_out gemm
  float*          wout_sl = xz;                                // 2 slices f32; after scan last-reads xzb

  dim3 b256(256);
  int gElem = (TOT + 255) / 256;

  // ---- block 1: inorm+bn+relu fused with transpose -> hT bf16 ----
  inorm_stats<<<dim3(Bc * Cc), b256, 0, stream>>>(x, m1, v1);
  bn_scale<<<dim3(1), dim3(128), 0, stream>>>(v1, bnsc);
  compute_h_t<<<dim3(32, Bc), b256, 0, stream>>>(x, m1, v1, bnsc, bn1_g, bn1_b, hT);
  cvt_pad_bf16<<<dim3(64), b256, 0, stream>>>(conv1_w, W1b, 128, 128, Cc, Cc);
  { // out1[b][o][n] = sum_c W1[o][c] * hT[b][n][c] + conv1_b[o]
    dim3 g(16, 1, Bc);
    gemm_mfma_bt<<<g, b256, 0, stream>>>(W1b, hT, out1, Nc, 128, 128, 128, Nc,
                                         0L, 2048L * 128, (long)Cc * Nc,
                                         1, 128, 0L, 3, conv1_b, nullptr, 0, 0, 0);
  }

  // ---- layernorm -> bf16 An ----
  ln_rows<<<dim3(ROWS), b256, 0, stream>>>(out1, ln_w, ln_b, An);

  // ---- W_in -> bf16 padded (8064 x 2016) in dead dtb region ----
  {
    long tot = (long)NP1 * KP1;
    cvt_pad_bf16<<<dim3((unsigned)((tot + 255) / 256)), b256, 0, stream>>>(
        W_in, Bwin, NP1, KP1, E2c, Nc);
  }

  // ---- xzb = An @ W_in^T  (MFMA bf16, XCD swizzle mode 1, bf16 out,
  //      epi=2: silu on z half) ----
  {
    gemm_mfma_bt<<<dim3(1024), b256, 0, stream>>>(
        An, Bwin, (float*)xzb, E2c, KP1, KP1, KP1, E2c,
        0L, 0L, 0L, 1, KP1, 0L, 2, nullptr, nullptr, 1, NP1, 1);
  }

  // ---- weight conversions for mamba-internal gemms (An now dead) ----
  cvt_pad_bf16<<<dim3((256 * 4000 + 255) / 256), b256, 0, stream>>>(
      W_x, Bwx, 256, 4000, EXc, DIc);
  cvt_pad_bf16<<<dim3((4096 * 128 + 255) / 256), b256, 0, stream>>>(
      W_dt, Bwdt, 4096, 128, DIc, RKc);

  // ---- depthwise conv + silu -> xc f32 + xcb bf16 (hT dead) ----
  {
    int tot = ROWS * DIc;
    dwconv_silu<<<dim3((tot + 255) / 256), b256, 0, stream>>>(
        xzb, (const float4*)convm_w, convm_b, xc, xcb, tot);
  }

  // ---- xdbl = xc @ W_x^T  (MFMA bf16, KS=4 slices) ----
  {
    dim3 g(2, ROWS / 128, 4);
    gemm_mfma_bt<<<g, b256, 0, stream>>>(xcb, Bwx, xdbl_sl, 256, DIc,
                                         DIc, DIc, 256, 0L, 0L, 0L,
                                         4, 1024, 2048L * 256, 0, nullptr, nullptr,
                                         0, 0, 0);
    int tot = 2048 * 144;
    reduce_xdbl<<<dim3((tot + 255) / 256), b256, 0, stream>>>(xdbl_sl, xdbl, xdbl_b);
  }

  // ---- dtv = softplus(xdbl_b @ W_dt^T + b_dt)  (MFMA bf16, epi=1) ----
  {
    dim3 g(4096 / 128, ROWS / 128, 1);
    gemm_mfma_bt<<<g, b256, 0, stream>>>(xdbl_b, Bwdt, dtb, DIc, 128,
                                         128, 128, DIc, 0L, 0L, 0L,
                                         1, 128, 0L, 1, b_dt, nullptr, 0, 0, 0);
  }

  // ---- W_out -> bf16 (2048 x 4000) in h region (xcb dead) ----
  {
    long tot = (long)2048 * DIc;
    cvt_pad_bf16<<<dim3((unsigned)((tot + 255) / 256)), b256, 0, stream>>>(
        W_out, Bwout, 2048, DIc, Nc, DIc);
  }

  // ---- selective scan (pipelined, 1 thread/(b,d)) -> yb bf16 ----
  scan_kernel<<<dim3((DIc + 255) / 256, Bc), b256, 0, stream>>>(
      dtb, xdbl, xc, xzb, A_log, D_p, yb);

  // ---- y @ W_out^T  (MFMA bf16, XCD swizzle mode 2, KS=2 slices) ----
  {
    gemm_mfma_bt<<<dim3(512), b256, 0, stream>>>(
        yb, Bwout, wout_sl, Nc, DIc, DIc, DIc, Nc,
        0L, 0L, 0L, 2, 2048, (long)TOT, 0, nullptr, nullptr, 2, 0, 0);
    reduce_slices<<<dim3(gElem), b256, 0, stream>>>(
        wout_sl, out1, (long)TOT, 2, TOT, 1);
  }

  // ---- block 3 on out1 -> d_out = conv3(h3) + conv3_b + x ----
  inorm_stats<<<dim3(Bc * Cc), b256, 0, stream>>>(out1, m1, v1);
  bn_scale<<<dim3(1), dim3(128), 0, stream>>>(v1, bnsc);
  compute_h_t<<<dim3(32, Bc), b256, 0, stream>>>(out1, m1, v1, bnsc, bn3_g, bn3_b, hT);
  cvt_pad_bf16<<<dim3(64), b256, 0, stream>>>(conv3_w, W3b, 128, 128, Cc, Cc);
  {
    dim3 g(16, 1, Bc);
    gemm_mfma_bt<<<g, b256, 0, stream>>>(W3b, hT, out, Nc, 128, 128, 128, Nc,
                                         0L, 2048L * 128, (long)Cc * Nc,
                                         1, 128, 0L, 3, conv3_b, x, 0, 0, 0);
  }
}